// Round 7
// baseline (248.264 us; speedup 1.0000x reference)
//
#include <hip/hip_runtime.h>
#include <hip/hip_bf16.h>
#include <hip/hip_cooperative_groups.h>

namespace cg = cooperative_groups;

// Problem constants (match reference)
#define BATCH 4096
#define NC    1024   // n_concepts (K)
#define NL    512    // n_lemmas   (N)
#define TSTEPS 50
#define GAMMA_C 0.95f
#define KAPPA_C 0.1f
#define FLOOR_C 1e-6f

typedef __attribute__((ext_vector_type(8))) short short8;  // 8 bf16 = 4 VGPRs
typedef __attribute__((ext_vector_type(4))) float f32x4;   // MFMA C/D frag

#define TM 128
#define TN 128
#define GK 32
#define SPLITK 4
#define NST (NC / SPLITK / GK)   // 8

// ---------------- packed split fp32 -> bf16 hi + bf16 lo (RNE both) --------
__device__ __forceinline__ void split2_pk(float x0, float x1,
                                          unsigned& hp, unsigned& lp) {
    union { __hip_bfloat162 b; unsigned u; } ch, cl;
    ch.b = __float22bfloat162_rn(make_float2(x0, x1));
    hp = ch.u;
    const float hf0 = __uint_as_float(hp << 16);
    const float hf1 = __uint_as_float(hp & 0xFFFF0000u);
    cl.b = __float22bfloat162_rn(make_float2(x0 - hf0, x1 - hf1));
    lp = cl.u;
}

// ------- full-wave (64-lane) sum, broadcast to all lanes, via DPP ----------
__device__ __forceinline__ float wave_sum_bcast(float x) {
    float f = x;
    f += __int_as_float(__builtin_amdgcn_update_dpp(
            0, __float_as_int(f), 0x111, 0xf, 0xf, true));   // row_shr:1
    f += __int_as_float(__builtin_amdgcn_update_dpp(
            0, __float_as_int(f), 0x112, 0xf, 0xf, true));   // row_shr:2
    f += __int_as_float(__builtin_amdgcn_update_dpp(
            0, __float_as_int(f), 0x114, 0xf, 0xf, true));   // row_shr:4
    f += __int_as_float(__builtin_amdgcn_update_dpp(
            0, __float_as_int(f), 0x118, 0xf, 0xf, true));   // row_shr:8
    f += __int_as_float(__builtin_amdgcn_update_dpp(
            0, __float_as_int(f), 0x142, 0xa, 0xf, true));   // row_bcast:15
    f += __int_as_float(__builtin_amdgcn_update_dpp(
            0, __float_as_int(f), 0x143, 0xc, 0xf, true));   // row_bcast:31
    return __int_as_float(__builtin_amdgcn_readlane(__float_as_int(f), 63));
}

// global -> LDS DMA, 16 B per lane; HW dest = readfirstlane(lds) + lane*16
__device__ __forceinline__ void glds16f(const float* g, float* l) {
    __builtin_amdgcn_global_load_lds(
        (__attribute__((address_space(1))) void*)(g),
        (__attribute__((address_space(3))) void*)(l), 16, 0, 0);
}

// ================= GEMM phase (R6 body, verified, unchanged) ================
// f32 operands staged direct via global_load_lds, hi/lo split in the
// fragment path, counted-vmcnt pipeline, XCD-aware relabel (all 16 blocks of
// an A m-panel on XCD mi>>2), rule-#21 both-sides XOR granule swizzle.
__device__ __forceinline__ void gemm_phase(const float* __restrict__ A,
                                           const float* __restrict__ W,
                                           float* __restrict__ Dp,
                                           int& mi_b_out, int& slot_out) {
    __shared__ float S[2][2][TM * GK];   // 64 KB

    const int tid  = threadIdx.x;
    const int lane = tid & 63;
    const int w    = tid >> 6;

    const int b    = blockIdx.x;             // 0..511
    const int xcd  = b & 7;
    const int slot = b >> 3;                 // 0..63
    const int mi_b = xcd * 4 + (slot & 3);   // 0..31 (xcd = mi_b>>2)
    const int nk   = slot >> 2;              // 0..15
    const int ni_b = nk & 3;                 // 0..3
    const int kz   = nk >> 2;                // 0..3
    mi_b_out = mi_b;
    slot_out = slot;

    const int m0 = mi_b * TM;
    const int n0 = ni_b * TN;
    const int kb = kz * (NC / SPLITK);

    const int srow = lane >> 3;                                  // 0..7
    const int scol = ((lane & 7) * 4) ^ ((srow & 7) << 2);       // XOR granule
    const float* gA = A + (size_t)(m0 + w * 32 + srow) * NC + kb + scol;
    const float* gB = W + (size_t)(n0 + w * 32 + srow) * NC + kb + scol;
    const int ldd = (w * 32) * GK;

    const int mw   = (w >> 1) * 64;
    const int nw   = (w & 1) * 64;
    const int sr   = lane & 15;
    const int quad = lane >> 4;
    const int swz = (sr & 7) << 2;
    const int c0  = (quad * 8) ^ swz;
    const int c1  = (quad * 8 + 4) ^ swz;
    const int rAo = (mw + sr) * GK;
    const int rBo = (nw + sr) * GK;

    f32x4 acc[4][4];
    #pragma unroll
    for (int i = 0; i < 4; ++i)
        #pragma unroll
        for (int j = 0; j < 4; ++j)
            acc[i][j] = (f32x4){0.f, 0.f, 0.f, 0.f};

    #define STAGE(buf, kofs)                                               \
        {                                                                  \
            const int ko = (kofs);                                         \
            _Pragma("unroll")                                              \
            for (int c = 0; c < 4; ++c) {                                  \
                glds16f(gA + (size_t)(c * 8) * NC + ko,                    \
                        &S[buf][0][ldd + c * 8 * GK]);                     \
                glds16f(gB + (size_t)(c * 8) * NC + ko,                    \
                        &S[buf][1][ldd + c * 8 * GK]);                     \
            }                                                              \
        }

    #define FRAG(ARR, ROFF, FH, FL)                                       \
        {                                                                  \
            const float4 f0 = *(const float4*)&S[CUR][ARR][(ROFF) + c0];   \
            const float4 f1 = *(const float4*)&S[CUR][ARR][(ROFF) + c1];   \
            uint4 hh, ll;                                                  \
            split2_pk(f0.x, f0.y, hh.x, ll.x);                             \
            split2_pk(f0.z, f0.w, hh.y, ll.y);                             \
            split2_pk(f1.x, f1.y, hh.z, ll.z);                             \
            split2_pk(f1.z, f1.w, hh.w, ll.w);                             \
            FH = *(const short8*)&hh;                                      \
            FL = *(const short8*)&ll;                                      \
        }

    #define KSTEP(CURV, VMSTR, DO_STAGE, NEXTK)                                \
        {                                                                      \
            const int CUR = (CURV);                                            \
            asm volatile("s_waitcnt vmcnt(" VMSTR ")" ::: "memory");           \
            __builtin_amdgcn_sched_barrier(0);                                 \
            __builtin_amdgcn_s_barrier();                                      \
            __builtin_amdgcn_sched_barrier(0);                                 \
            short8 afh[4], afl[4], bfh[4], bfl[4];                             \
            _Pragma("unroll")                                                  \
            for (int mi = 0; mi < 4; ++mi)                                     \
                FRAG(0, rAo + mi * 16 * GK, afh[mi], afl[mi]);                 \
            _Pragma("unroll")                                                  \
            for (int ni = 0; ni < 4; ++ni)                                     \
                FRAG(1, rBo + ni * 16 * GK, bfh[ni], bfl[ni]);                 \
            _Pragma("unroll")                                                  \
            for (int mi = 0; mi < 4; ++mi) {                                   \
                _Pragma("unroll")                                              \
                for (int ni = 0; ni < 4; ++ni) {                               \
                    acc[mi][ni] = __builtin_amdgcn_mfma_f32_16x16x32_bf16(     \
                        afh[mi], bfh[ni], acc[mi][ni], 0, 0, 0);               \
                    acc[mi][ni] = __builtin_amdgcn_mfma_f32_16x16x32_bf16(     \
                        afh[mi], bfl[ni], acc[mi][ni], 0, 0, 0);               \
                    acc[mi][ni] = __builtin_amdgcn_mfma_f32_16x16x32_bf16(     \
                        afl[mi], bfh[ni], acc[mi][ni], 0, 0, 0);               \
                }                                                              \
            }                                                                  \
            __builtin_amdgcn_sched_barrier(0);                                 \
            __builtin_amdgcn_s_barrier();                                      \
            __builtin_amdgcn_sched_barrier(0);                                 \
            if (DO_STAGE) STAGE(CUR, NEXTK);                                   \
        }

    STAGE(0, 0);
    STAGE(1, GK);
    #pragma unroll 2
    for (int s = 0; s < NST - 2; ++s)
        KSTEP((s & 1), "8", true, (s + 2) * GK);
    KSTEP(0, "8", false, 0);
    KSTEP(1, "0", false, 0);

    #undef STAGE
    #undef FRAG
    #undef KSTEP

    // epilogue: C/D layout col = lane&15, row = quad*4 + reg  [m89/m91]
    float* Dz = Dp + (size_t)kz * BATCH * NL;
    #pragma unroll
    for (int mi = 0; mi < 4; ++mi) {
        #pragma unroll
        for (int ni = 0; ni < 4; ++ni) {
            const int col = n0 + nw + ni * 16 + sr;
            #pragma unroll
            for (int r = 0; r < 4; ++r) {
                const int row = m0 + mw + mi * 16 + quad * 4 + r;
                Dz[(size_t)row * NL + col] = acc[mi][ni][r];
            }
        }
    }
}

// ============ recurrence + selection for NR consecutive rows ================
// Numerics identical (same association order) to the verified iterate_select.
template<int NR>
__device__ __forceinline__ void iterate_rows(const float* __restrict__ Dp,
                                             const int row0, const int lane,
                                             float* __restrict__ a_out,
                                             float* __restrict__ sel_out,
                                             float* __restrict__ conf_out) {
    float d[NR][8];
    #pragma unroll
    for (int rr = 0; rr < NR; ++rr) {
        float4 v[SPLITK][2];
        #pragma unroll
        for (int s = 0; s < SPLITK; ++s) {
            const float4* ps = (const float4*)(Dp + (size_t)s * BATCH * NL
                                               + (size_t)(row0 + rr) * NL + lane * 8);
            v[s][0] = ps[0];
            v[s][1] = ps[1];
        }
        d[rr][0] = v[0][0].x; d[rr][1] = v[0][0].y; d[rr][2] = v[0][0].z; d[rr][3] = v[0][0].w;
        d[rr][4] = v[0][1].x; d[rr][5] = v[0][1].y; d[rr][6] = v[0][1].z; d[rr][7] = v[0][1].w;
        #pragma unroll
        for (int s = 1; s < SPLITK; ++s) {
            d[rr][0] += v[s][0].x; d[rr][1] += v[s][0].y; d[rr][2] += v[s][0].z; d[rr][3] += v[s][0].w;
            d[rr][4] += v[s][1].x; d[rr][5] += v[s][1].y; d[rr][6] += v[s][1].z; d[rr][7] += v[s][1].w;
        }
    }

    float a[NR][8];
    #pragma unroll
    for (int rr = 0; rr < NR; ++rr)
        #pragma unroll
        for (int j = 0; j < 8; ++j) a[rr][j] = 0.f;

    const float K1 = 1.0f + KAPPA_C;

    for (int t = 0; t < TSTEPS; ++t) {
        #pragma unroll
        for (int rr = 0; rr < NR; ++rr)
            #pragma unroll
            for (int j = 0; j < 8; ++j)
                a[rr][j] = fmaf(GAMMA_C, a[rr][j], d[rr][j]);

        float S[NR];
        #pragma unroll
        for (int rr = 0; rr < NR; ++rr) {
            float t4a = a[rr][0] + a[rr][4], t4b = a[rr][1] + a[rr][5];
            float t4c = a[rr][2] + a[rr][6], t4d = a[rr][3] + a[rr][7];
            float t2a = t4a + t4c, t2b = t4b + t4d;
            S[rr] = wave_sum_bcast(t2a + t2b);
        }

        #pragma unroll
        for (int rr = 0; rr < NR; ++rr) {
            const float h = -KAPPA_C * S[rr];
            #pragma unroll
            for (int j = 0; j < 8; ++j) {
                const float v = fmaf(K1, a[rr][j], h);
                a[rr][j] = v > 0.f ? v : 0.f;
            }
        }
    }

    #pragma unroll
    for (int rr = 0; rr < NR; ++rr) {
        const int row = row0 + rr;
        float m4a = fmaxf(a[rr][0], a[rr][4]), m4b = fmaxf(a[rr][1], a[rr][5]);
        float m4c = fmaxf(a[rr][2], a[rr][6]), m4d = fmaxf(a[rr][3], a[rr][7]);
        float peak = fmaxf(fmaxf(m4a, m4b), fmaxf(m4c, m4d));
        float s4a = a[rr][0] + a[rr][4], s4b = a[rr][1] + a[rr][5];
        float s4c = a[rr][2] + a[rr][6], s4d = a[rr][3] + a[rr][7];
        float ssum = wave_sum_bcast((s4a + s4b) + (s4c + s4d));

        #pragma unroll
        for (int m = 1; m < 64; m <<= 1)
            peak = fmaxf(peak, __shfl_xor(peak, m, 64));

        const float mean = ssum * (1.0f / (float)NL);
        const float conf = peak / fmaxf(mean, FLOOR_C);

        int idx = 0x7fffffff;
        #pragma unroll
        for (int j = 0; j < 8; ++j)
            if (a[rr][j] == peak) idx = min(idx, lane * 8 + j);
        #pragma unroll
        for (int m = 1; m < 64; m <<= 1)
            idx = min(idx, __shfl_xor(idx, m, 64));

        float4 o0, o1;
        o0.x = a[rr][0]; o0.y = a[rr][1]; o0.z = a[rr][2]; o0.w = a[rr][3];
        o1.x = a[rr][4]; o1.y = a[rr][5]; o1.z = a[rr][6]; o1.w = a[rr][7];
        float4* arp = (float4*)(a_out + (size_t)row * NL + lane * 8);
        arp[0] = o0; arp[1] = o1;

        if (lane == 0) {
            if (sel_out)  sel_out[row]  = (float)idx;
            if (conf_out) conf_out[row] = conf;
        }
    }
}

// ===================== fused: GEMM + grid.sync + recurrence =================
// 512 blocks (2/CU, co-resident: 64 KB LDS + ~132 VGPR per 4-wave block).
// Phase-2 rows of panel mi are read on XCD mi>>2 — the same XCD that wrote
// ALL (ni,kz) D-partials of that panel -> reads are XCD-L2-local.
__global__ __launch_bounds__(256)
void fused_gi(const float* __restrict__ A, const float* __restrict__ W,
              float* __restrict__ D, float* __restrict__ a_out,
              float* __restrict__ sel_out, float* __restrict__ conf_out) {
    int mi_b, slot;
    gemm_phase(A, W, D, mi_b, slot);

    __threadfence();             // release D writes device-wide
    cg::this_grid().sync();      // all partials complete

    const int lane = threadIdx.x & 63;
    const int w    = threadIdx.x >> 6;
    const int nk2  = slot >> 2;                        // 0..15
    const int row0 = mi_b * 128 + nk2 * 8 + w * 2;     // 8 rows/block, 2/wave
    iterate_rows<2>(D, row0, lane, a_out, sel_out, conf_out);
}

// ===================== fallback: verified R6 2-kernel path ==================
__global__ __launch_bounds__(256)
void gemm_f32stage(const float* __restrict__ A, const float* __restrict__ W,
                   float* __restrict__ Dp) {
    int mi_b, slot;
    gemm_phase(A, W, Dp, mi_b, slot);
}

__global__ __launch_bounds__(256)
void iterate_select(const float* __restrict__ Dp,
                    float* __restrict__ a_out,
                    float* __restrict__ sel_out, float* __restrict__ conf_out) {
    const int lane = threadIdx.x & 63;
    const int wave = threadIdx.x >> 6;
    const int row  = blockIdx.x * 4 + wave;
    iterate_rows<1>(Dp, row, lane, a_out, sel_out, conf_out);
}

extern "C" void kernel_launch(void* const* d_in, const int* in_sizes, int n_in,
                              void* d_out, int out_size, void* d_ws, size_t ws_size,
                              hipStream_t stream) {
    const float* c_lex = (const float*)d_in[0];
    const float* W     = (const float*)d_in[1];
    // d_in[2] = a0 (zeros at every reset; recurrence inits a=0 directly)

    // workspace: 4 D-partials only (33.6 MB)
    float* D = (float*)d_ws;

    float* a_out = (float*)d_out;
    float* sel   = nullptr;
    float* conf  = nullptr;
    const int base = BATCH * NL;
    if (out_size >= base + 2 * BATCH) {        // (a, selected, confidence)
        sel  = a_out + base;
        conf = a_out + base + BATCH;
    } else if (out_size >= base + BATCH) {     // (a, confidence)
        conf = a_out + base;
    }

    void* args[] = {(void*)&c_lex, (void*)&W, (void*)&D,
                    (void*)&a_out, (void*)&sel, (void*)&conf};
    hipError_t e = hipLaunchCooperativeKernel((const void*)fused_gi,
                                              dim3(512), dim3(256),
                                              args, 0, stream);
    if (e != hipSuccess) {
        // fallback: verified R6 two-dispatch pipeline
        gemm_f32stage<<<dim3(512), 256, 0, stream>>>(c_lex, W, D);
        iterate_select<<<dim3(BATCH / 4), 256, 0, stream>>>(D, a_out, sel, conf);
    }
}

// Round 8
// 107.346 us; speedup vs baseline: 2.3127x; 2.3127x over previous
//
#include <hip/hip_runtime.h>
#include <hip/hip_bf16.h>

// Problem constants (match reference)
#define BATCH 4096
#define NC    1024   // n_concepts (K)
#define NL    512    // n_lemmas   (N)
#define TSTEPS 50
#define GAMMA_C 0.95f
#define KAPPA_C 0.1f
#define FLOOR_C 1e-6f

typedef __attribute__((ext_vector_type(8))) short short8;  // 8 bf16 = 4 VGPRs
typedef __attribute__((ext_vector_type(4))) float f32x4;   // MFMA C/D frag

#define TM 128
#define TN 128
#define GK 32
#define SPLITK 4
#define NST (NC / SPLITK / GK)   // 8

// ---------------- packed split fp32 -> bf16 hi + bf16 lo (RNE both) --------
__device__ __forceinline__ void split2_pk(float x0, float x1,
                                          unsigned& hp, unsigned& lp) {
    union { __hip_bfloat162 b; unsigned u; } ch, cl;
    ch.b = __float22bfloat162_rn(make_float2(x0, x1));
    hp = ch.u;
    const float hf0 = __uint_as_float(hp << 16);
    const float hf1 = __uint_as_float(hp & 0xFFFF0000u);
    cl.b = __float22bfloat162_rn(make_float2(x0 - hf0, x1 - hf1));
    lp = cl.u;
}

// ------- full-wave (64-lane) sum, broadcast to all lanes, via DPP ----------
__device__ __forceinline__ float wave_sum_bcast(float x) {
    float f = x;
    f += __int_as_float(__builtin_amdgcn_update_dpp(
            0, __float_as_int(f), 0x111, 0xf, 0xf, true));   // row_shr:1
    f += __int_as_float(__builtin_amdgcn_update_dpp(
            0, __float_as_int(f), 0x112, 0xf, 0xf, true));   // row_shr:2
    f += __int_as_float(__builtin_amdgcn_update_dpp(
            0, __float_as_int(f), 0x114, 0xf, 0xf, true));   // row_shr:4
    f += __int_as_float(__builtin_amdgcn_update_dpp(
            0, __float_as_int(f), 0x118, 0xf, 0xf, true));   // row_shr:8
    f += __int_as_float(__builtin_amdgcn_update_dpp(
            0, __float_as_int(f), 0x142, 0xa, 0xf, true));   // row_bcast:15
    f += __int_as_float(__builtin_amdgcn_update_dpp(
            0, __float_as_int(f), 0x143, 0xc, 0xf, true));   // row_bcast:31
    return __int_as_float(__builtin_amdgcn_readlane(__float_as_int(f), 63));
}

// global -> LDS DMA, 16 B per lane; HW dest = readfirstlane(lds) + lane*16
__device__ __forceinline__ void glds16f(const float* g, float* l) {
    __builtin_amdgcn_global_load_lds(
        (__attribute__((address_space(1))) void*)(g),
        (__attribute__((address_space(3))) void*)(l), 16, 0, 0);
}

// --------- MFMA GEMM, f32 operands staged directly (no convert pass) --------
// Verified R6 structure (107.9 us total): f32 A/W staged via global_load_lds,
// hi/lo split in the fragment path, counted-vmcnt pipeline (vmcnt(8) steady,
// 0 only at the tail), XCD-aware relabel (all 16 blocks of an A m-panel on
// one XCD -> panel L2-resident), rule-#21 both-sides XOR granule swizzle.
// R7 lesson: cooperative fusion of this exact body = 168 us (coop-mode
// overhead ~130 us regardless of occupancy/structure) -> regular dispatches.
__global__ __launch_bounds__(256)
void gemm_f32stage(const float* __restrict__ A, const float* __restrict__ W,
                   float* __restrict__ Dp) {
    // [buf][arr: 0=A,1=B][128 rows][32 floats] = 64 KB
    __shared__ float S[2][2][TM * GK];

    const int tid  = threadIdx.x;
    const int lane = tid & 63;
    const int w    = tid >> 6;

    const int b    = blockIdx.x;             // 0..511
    const int xcd  = b & 7;
    const int slot = b >> 3;                 // 0..63
    const int mi_b = xcd * 4 + (slot & 3);   // 0..31
    const int nk   = slot >> 2;              // 0..15
    const int ni_b = nk & 3;                 // 0..3
    const int kz   = nk >> 2;                // 0..3

    const int m0 = mi_b * TM;
    const int n0 = ni_b * TN;
    const int kb = kz * (NC / SPLITK);

    const int srow = lane >> 3;                                  // 0..7
    const int scol = ((lane & 7) * 4) ^ ((srow & 7) << 2);       // XOR granule
    const float* gA = A + (size_t)(m0 + w * 32 + srow) * NC + kb + scol;
    const float* gB = W + (size_t)(n0 + w * 32 + srow) * NC + kb + scol;
    const int ldd = (w * 32) * GK;

    const int mw   = (w >> 1) * 64;
    const int nw   = (w & 1) * 64;
    const int sr   = lane & 15;
    const int quad = lane >> 4;
    const int swz = (sr & 7) << 2;
    const int c0  = (quad * 8) ^ swz;
    const int c1  = (quad * 8 + 4) ^ swz;
    const int rAo = (mw + sr) * GK;
    const int rBo = (nw + sr) * GK;

    f32x4 acc[4][4];
    #pragma unroll
    for (int i = 0; i < 4; ++i)
        #pragma unroll
        for (int j = 0; j < 4; ++j)
            acc[i][j] = (f32x4){0.f, 0.f, 0.f, 0.f};

    // 8 glds16f per wave per stage (A: 4, B: 4) -> vmcnt +8 per STAGE
    #define STAGE(buf, kofs)                                               \
        {                                                                  \
            const int ko = (kofs);                                         \
            _Pragma("unroll")                                              \
            for (int c = 0; c < 4; ++c) {                                  \
                glds16f(gA + (size_t)(c * 8) * NC + ko,                    \
                        &S[buf][0][ldd + c * 8 * GK]);                     \
                glds16f(gB + (size_t)(c * 8) * NC + ko,                    \
                        &S[buf][1][ldd + c * 8 * GK]);                     \
            }                                                              \
        }

    // build hi/lo bf16 fragments from 8 staged f32 (two swizzled float4s)
    #define FRAG(ARR, ROFF, FH, FL)                                        \
        {                                                                  \
            const float4 f0 = *(const float4*)&S[CUR][ARR][(ROFF) + c0];   \
            const float4 f1 = *(const float4*)&S[CUR][ARR][(ROFF) + c1];   \
            uint4 hh, ll;                                                  \
            split2_pk(f0.x, f0.y, hh.x, ll.x);                             \
            split2_pk(f0.z, f0.w, hh.y, ll.y);                             \
            split2_pk(f1.x, f1.y, hh.z, ll.z);                             \
            split2_pk(f1.z, f1.w, hh.w, ll.w);                             \
            FH = *(const short8*)&hh;                                      \
            FL = *(const short8*)&ll;                                      \
        }

    // one pipelined K-step; VMSTR = vmcnt immediate (8 steady-state, 0 last)
    #define KSTEP(CURV, VMSTR, DO_STAGE, NEXTK)                                \
        {                                                                      \
            const int CUR = (CURV);                                            \
            asm volatile("s_waitcnt vmcnt(" VMSTR ")" ::: "memory");           \
            __builtin_amdgcn_sched_barrier(0);                                 \
            __builtin_amdgcn_s_barrier();                                      \
            __builtin_amdgcn_sched_barrier(0);                                 \
            short8 afh[4], afl[4], bfh[4], bfl[4];                             \
            _Pragma("unroll")                                                  \
            for (int mi = 0; mi < 4; ++mi)                                     \
                FRAG(0, rAo + mi * 16 * GK, afh[mi], afl[mi]);                 \
            _Pragma("unroll")                                                  \
            for (int ni = 0; ni < 4; ++ni)                                     \
                FRAG(1, rBo + ni * 16 * GK, bfh[ni], bfl[ni]);                 \
            _Pragma("unroll")                                                  \
            for (int mi = 0; mi < 4; ++mi) {                                   \
                _Pragma("unroll")                                              \
                for (int ni = 0; ni < 4; ++ni) {                               \
                    acc[mi][ni] = __builtin_amdgcn_mfma_f32_16x16x32_bf16(     \
                        afh[mi], bfh[ni], acc[mi][ni], 0, 0, 0);               \
                    acc[mi][ni] = __builtin_amdgcn_mfma_f32_16x16x32_bf16(     \
                        afh[mi], bfl[ni], acc[mi][ni], 0, 0, 0);               \
                    acc[mi][ni] = __builtin_amdgcn_mfma_f32_16x16x32_bf16(     \
                        afl[mi], bfh[ni], acc[mi][ni], 0, 0, 0);               \
                }                                                              \
            }                                                                  \
            __builtin_amdgcn_sched_barrier(0);                                 \
            __builtin_amdgcn_s_barrier();                                      \
            __builtin_amdgcn_sched_barrier(0);                                 \
            if (DO_STAGE) STAGE(CUR, NEXTK);                                   \
        }

    // prologue: stages 0 and 1 in flight (16 DMA ops/wave outstanding)
    STAGE(0, 0);
    STAGE(1, GK);

    // steady state: buffer overwritten only after the barrier that ends its
    // readers; each stage's loads get a full step before their vmcnt(8) wait.
    #pragma unroll 2
    for (int s = 0; s < NST - 2; ++s)
        KSTEP((s & 1), "8", true, (s + 2) * GK);
    // peeled tail
    KSTEP(0, "8", false, 0);
    KSTEP(1, "0", false, 0);

    // epilogue: C/D layout col = lane&15, row = quad*4 + reg  [m89/m91]
    float* Dz = Dp + (size_t)kz * BATCH * NL;
    #pragma unroll
    for (int mi = 0; mi < 4; ++mi) {
        #pragma unroll
        for (int ni = 0; ni < 4; ++ni) {
            const int col = n0 + nw + ni * 16 + sr;
            #pragma unroll
            for (int r = 0; r < 4; ++r) {
                const int row = m0 + mw + mi * 16 + quad * 4 + r;
                Dz[(size_t)row * NL + col] = acc[mi][ni][r];
            }
        }
    }
}

// ------ 50-step recurrence + selection: 64 lanes per row, 8 cols/lane -------
template<int SK>
__global__ __launch_bounds__(256)
void iterate_select(const float* __restrict__ Dp,
                    float* __restrict__ a_out,
                    float* __restrict__ sel_out, float* __restrict__ conf_out) {
    const int lane = threadIdx.x & 63;
    const int wave = threadIdx.x >> 6;
    const int row  = blockIdx.x * 4 + wave;

    float d[8];
    {
        float4 v[SK][2];
        #pragma unroll
        for (int s = 0; s < SK; ++s) {
            const float4* ps = (const float4*)(Dp + (size_t)s * BATCH * NL
                                               + (size_t)row * NL + lane * 8);
            v[s][0] = ps[0];
            v[s][1] = ps[1];
        }
        d[0] = v[0][0].x; d[1] = v[0][0].y; d[2] = v[0][0].z; d[3] = v[0][0].w;
        d[4] = v[0][1].x; d[5] = v[0][1].y; d[6] = v[0][1].z; d[7] = v[0][1].w;
        #pragma unroll
        for (int s = 1; s < SK; ++s) {
            d[0] += v[s][0].x; d[1] += v[s][0].y; d[2] += v[s][0].z; d[3] += v[s][0].w;
            d[4] += v[s][1].x; d[5] += v[s][1].y; d[6] += v[s][1].z; d[7] += v[s][1].w;
        }
    }

    float a[8];
    #pragma unroll
    for (int j = 0; j < 8; ++j) a[j] = 0.f;

    const float K1 = 1.0f + KAPPA_C;

    for (int t = 0; t < TSTEPS; ++t) {
        #pragma unroll
        for (int j = 0; j < 8; ++j) a[j] = fmaf(GAMMA_C, a[j], d[j]);

        float t4a = a[0] + a[4], t4b = a[1] + a[5], t4c = a[2] + a[6], t4d = a[3] + a[7];
        float t2a = t4a + t4c, t2b = t4b + t4d;
        const float S = wave_sum_bcast(t2a + t2b);

        const float h = -KAPPA_C * S;
        #pragma unroll
        for (int j = 0; j < 8; ++j) {
            const float v = fmaf(K1, a[j], h);
            a[j] = v > 0.f ? v : 0.f;
        }
    }

    // ---- epilogue (runs once): peak, sum, confidence, first-index argmax ----
    float m4a = fmaxf(a[0], a[4]), m4b = fmaxf(a[1], a[5]);
    float m4c = fmaxf(a[2], a[6]), m4d = fmaxf(a[3], a[7]);
    float peak = fmaxf(fmaxf(m4a, m4b), fmaxf(m4c, m4d));
    float s4a = a[0] + a[4], s4b = a[1] + a[5], s4c = a[2] + a[6], s4d = a[3] + a[7];
    float ssum = wave_sum_bcast((s4a + s4b) + (s4c + s4d));

    #pragma unroll
    for (int m = 1; m < 64; m <<= 1)
        peak = fmaxf(peak, __shfl_xor(peak, m, 64));

    const float mean = ssum * (1.0f / (float)NL);
    const float conf = peak / fmaxf(mean, FLOOR_C);

    int idx = 0x7fffffff;
    #pragma unroll
    for (int j = 0; j < 8; ++j)
        if (a[j] == peak) idx = min(idx, lane * 8 + j);
    #pragma unroll
    for (int m = 1; m < 64; m <<= 1)
        idx = min(idx, __shfl_xor(idx, m, 64));

    float4* ar = (float4*)(a_out + (size_t)row * NL + lane * 8);
    float4 o0, o1;
    o0.x = a[0]; o0.y = a[1]; o0.z = a[2]; o0.w = a[3];
    o1.x = a[4]; o1.y = a[5]; o1.z = a[6]; o1.w = a[7];
    ar[0] = o0; ar[1] = o1;

    if (lane == 0) {
        if (sel_out)  sel_out[row]  = (float)idx;
        if (conf_out) conf_out[row] = conf;
    }
}

extern "C" void kernel_launch(void* const* d_in, const int* in_sizes, int n_in,
                              void* d_out, int out_size, void* d_ws, size_t ws_size,
                              hipStream_t stream) {
    const float* c_lex = (const float*)d_in[0];
    const float* W     = (const float*)d_in[1];
    // d_in[2] = a0 (zeros at every reset; recurrence inits a=0 directly)

    // workspace: 4 D-partials only (33.6 MB)
    float* D = (float*)d_ws;

    float* a_out = (float*)d_out;
    float* sel   = nullptr;
    float* conf  = nullptr;
    const int base = BATCH * NL;
    if (out_size >= base + 2 * BATCH) {        // (a, selected, confidence)
        sel  = a_out + base;
        conf = a_out + base + BATCH;
    } else if (out_size >= base + BATCH) {     // (a, confidence)
        conf = a_out + base;
    }

    // 1) MFMA GEMM: f32 operands staged direct, counted-vmcnt, splitK=4,
    //    XCD-swizzled 512 blocks (2/CU)
    gemm_f32stage<<<dim3(512), 256, 0, stream>>>(c_lex, W, D);

    // 2) recurrence + selection: 1 row/wave, 4 waves/SIMD, DPP row-sum
    iterate_select<SPLITK><<<dim3(BATCH / 4), 256, 0, stream>>>(D, a_out, sel, conf);
}